// Round 6
// baseline (205.486 us; speedup 1.0000x reference)
//
#include <hip/hip_runtime.h>

// Problem constants (fixed by setup_inputs):
//   x: [B=64, D=64, H=32, W=32] fp32   -> N = B*H*W = 65536 rows of D=64
//   codebook: [K=512, D=64] fp32
// Output layout (all fp32, concatenated flat in return order):
//   [0 .. 4194304)        quant_out [B,D,H,W]
//   [4194304]             loss
//   [4194305]             perplexity
//   [4194306 .. +65536)   encoding_indice [B, H*W] (as float)
//   [4259842 .. +32768)   index_program [B,K]
//   [4292610 .. +32768)   softmax_histogram [B,K]

#define OFF_LOSS 4194304
#define OFF_PERP 4194305
#define OFF_ENC  4194306
#define OFF_IP   4259842
#define OFF_SH   4292610

// Workspace layout (floats). Requires ws_size >= 561664*4 B = 2.25 MB.
//   cbT  [4][64][128]        chunk-major transposed codebook
//   ce2  [512]               ||e_k||^2
//   sh partials [1024][512]  per-block softmax-histogram partial
//   loss partials [1024*4]   per-wave loss partial
#define WS_CBT   0
#define WS_CE2   32768
#define WS_SHP   33280
#define WS_LOSS  557568

// R13 change (LDS-bandwidth attack; math bit-identical per (row,k)):
//  - R12 cleaned traffic (WRITE 20.9 MB ideal, 0 conflicts) but VALUBusy=39%
//    at 126 us: LDS pipe is the limit. Per wave: 256 B-reads (32 distinct
//    addrs = full 512 B each, ~8-12 cyc) + 256 A-reads for 4096 FMA -> B-read
//    serialization alone ~80 us across the CUs.
//  - Fix: register tile 4x16 -> 8x16 (block 32x512 -> 64x512, 1024 blocks).
//    Per d: 2 broadcast A-reads (2 distinct addrs/wave: free) + 1 B-read for
//    32 FMA. Expensive B-read traffic HALVES. Eight f16v SSA accumulators
//    (128 VGPR, no allocas -> no spill); LDS 50.4 KB -> 2 blocks/CU, ~200
//    VGPR -> 2 waves/SIMD: consistent 8 waves/CU.
//  - cbT layout, vq_prep, chunking, col->k map, pv staging: unchanged.

typedef float f16v __attribute__((ext_vector_type(16)));

__global__ __launch_bounds__(256) void vq_prep(const float* __restrict__ cb,
                                               float* __restrict__ ws)
{
    const int t  = blockIdx.x * 256 + threadIdx.x;   // 0..8191
    const int kg = t >> 4;                           // code 0..511
    const int j  = t & 15;                           // float4 index along D
    const float4 v = ((const float4*)cb)[(kg << 4) + j];
    float pr = v.x * v.x + v.y * v.y + v.z * v.z + v.w * v.w;
    #pragma unroll
    for (int off = 1; off < 16; off <<= 1) pr += __shfl_xor(pr, off, 16);
    if (j == 0) ws[WS_CE2 + kg] = pr;
    // transposed, chunk-major: ws[WS_CBT + kc*8192 + d*128 + kl]
    const int kc = kg >> 7, kl = kg & 127;
    float* base = ws + WS_CBT + (kc << 13) + (j << 9) + kl;   // d = 4*j
    base[0]   = v.x;
    base[128] = v.y;
    base[256] = v.z;
    base[384] = v.w;
}

// ---- macro kit: all acc element indices are integer literals ----
#define FMA4(ACC, AV, K4) \
    ACC[(K4) + 0] = fmaf((AV), bq.x, ACC[(K4) + 0]); \
    ACC[(K4) + 1] = fmaf((AV), bq.y, ACC[(K4) + 1]); \
    ACC[(K4) + 2] = fmaf((AV), bq.z, ACC[(K4) + 2]); \
    ACC[(K4) + 3] = fmaf((AV), bq.w, ACC[(K4) + 3]);

#define ST_CST() do { \
    float4* c4 = (float4*)csT; \
    c4[t] = pv0; c4[256 + t] = pv1; c4[512 + t] = pv2; c4[768 + t] = pv3; \
    c4[1024 + t] = pv4; c4[1280 + t] = pv5; c4[1536 + t] = pv6; c4[1792 + t] = pv7; \
} while (0)

#define PREFETCH(KC1) do { \
    pv0 = cbT4[((KC1) << 11) + t];        pv1 = cbT4[((KC1) << 11) + 256 + t]; \
    pv2 = cbT4[((KC1) << 11) + 512 + t];  pv3 = cbT4[((KC1) << 11) + 768 + t]; \
    pv4 = cbT4[((KC1) << 11) + 1024 + t]; pv5 = cbT4[((KC1) << 11) + 1280 + t]; \
    pv6 = cbT4[((KC1) << 11) + 1536 + t]; pv7 = cbT4[((KC1) << 11) + 1792 + t]; \
} while (0)

// One 128-code chunk: stage csT, prefetch next, 64-d FMA sweep.
// Per (row,k): d ascending within chunk, chunks ascending -- same fmaf
// chain as R12. 8 rows x 4 cols per d from 2 broadcast A-reads + 1 B-read.
#define GEMM_CHUNK(KC) do { \
    __syncthreads(); \
    ST_CST(); \
    if ((KC) < 3) PREFETCH((KC) + 1); \
    __syncthreads(); \
    _Pragma("unroll 2") \
    for (int db = 0; db < 16; ++db) { \
        const float* cbase = &csT[(db << 9) + (tc << 2)]; \
        _Pragma("unroll") \
        for (int j = 0; j < 4; ++j) { \
            const int d = (db << 2) + j; \
            const float4 a0 = *(const float4*)&xs[(d << 6) + (tr << 3)]; \
            const float4 a1 = *(const float4*)&xs[(d << 6) + (tr << 3) + 4]; \
            const float4 bq = *(const float4*)&cbase[j << 7]; \
            FMA4(acc0, a0.x, (KC) << 2) \
            FMA4(acc1, a0.y, (KC) << 2) \
            FMA4(acc2, a0.z, (KC) << 2) \
            FMA4(acc3, a0.w, (KC) << 2) \
            FMA4(acc4, a1.x, (KC) << 2) \
            FMA4(acc5, a1.y, (KC) << 2) \
            FMA4(acc6, a1.z, (KC) << 2) \
            FMA4(acc7, a1.w, (KC) << 2) \
        } \
    } \
} while (0)

#define EPI_C(C, ACC) { \
    const int k = (((C) >> 2) << 7) + (tc << 2) + ((C) & 3); \
    const float t1 = xxr + ce2[k]; \
    const float dist = t1 - 2.f * ACC[C]; \
    ACC[C] = dist; \
    if (dist < m) { m = dist; bk = k; } }

#define EXP_C(C, ACC) { \
    const float e = __expf(m - ACC[C]); \
    ACC[C] = e; z += e; }

#define ROW_EPI(I, ACC, INVZ) do { \
    const int row = (tr << 3) + (I); \
    const float xxr = sxx[row]; \
    float m = 1e30f; int bk = 0; \
    EPI_C(0, ACC)  EPI_C(1, ACC)  EPI_C(2, ACC)  EPI_C(3, ACC) \
    EPI_C(4, ACC)  EPI_C(5, ACC)  EPI_C(6, ACC)  EPI_C(7, ACC) \
    EPI_C(8, ACC)  EPI_C(9, ACC)  EPI_C(10, ACC) EPI_C(11, ACC) \
    EPI_C(12, ACC) EPI_C(13, ACC) EPI_C(14, ACC) EPI_C(15, ACC) \
    _Pragma("unroll") \
    for (int off = 1; off < 32; off <<= 1) { \
        const float mo = __shfl_xor(m, off, 32); \
        const int   ko = __shfl_xor(bk, off, 32); \
        if (mo < m || (mo == m && ko < bk)) { m = mo; bk = ko; } \
    } \
    float z = 0.f; \
    EXP_C(0, ACC)  EXP_C(1, ACC)  EXP_C(2, ACC)  EXP_C(3, ACC) \
    EXP_C(4, ACC)  EXP_C(5, ACC)  EXP_C(6, ACC)  EXP_C(7, ACC) \
    EXP_C(8, ACC)  EXP_C(9, ACC)  EXP_C(10, ACC) EXP_C(11, ACC) \
    EXP_C(12, ACC) EXP_C(13, ACC) EXP_C(14, ACC) EXP_C(15, ACC) \
    _Pragma("unroll") \
    for (int off = 1; off < 32; off <<= 1) z += __shfl_xor(z, off, 32); \
    INVZ = 1.f / z; \
    if (tc == 0) { \
        sidx[row] = bk; \
        enc[((size_t)b << 10) + row0 + row] = (float)bk; \
    } \
} while (0)

#define HIST_C(C) { \
    const int k = (((C) >> 2) << 7) + (tc << 2) + ((C) & 3); \
    float cs = 0.f; \
    cs += acc0[C] * invz0; cs += acc1[C] * invz1; \
    cs += acc2[C] * invz2; cs += acc3[C] * invz3; \
    cs += acc4[C] * invz4; cs += acc5[C] * invz5; \
    cs += acc6[C] * invz6; cs += acc7[C] * invz7; \
    atomicAdd(&shist[k], cs); }

__global__ __launch_bounds__(256, 1) void vq_main(
    const float* __restrict__ x, const float* __restrict__ cb,
    const float* __restrict__ wsc,   // cbT + ce2 (read-only region)
    float* __restrict__ wso,         // sh + loss partials (write-only region)
    float* __restrict__ out)
{
    __shared__ float  xs[64 * 64];     // xs[d*64 + r], transposed x tile (64 rows)
    __shared__ float  csT[64 * 128];   // [d][k] for current 128-code chunk
    __shared__ float  ce2[512];        // ||e_k||^2 (fp32)
    __shared__ float  sxx[64];         // ||x_r||^2 (fp32) per row
    __shared__ int    sidx[64];        // argmin code per row

    const int t    = threadIdx.x;
    const int blk  = blockIdx.x;        // 0..1023
    const int b    = blk >> 4;          // batch index
    const int row0 = (blk & 15) << 6;   // row offset within batch (H*W space)
    const int tr   = t >> 5;            // 0..7  (row group: rows tr*8..tr*8+7)
    const int tc   = t & 31;            // 0..31 (col group)

    const float4* cbT4 = (const float4*)(wsc + WS_CBT);

    // ---- stage x tile as float4 (1024 float4, 4 per thread, coalesced) ----
    {
        const float4* xb4 = (const float4*)(x + ((size_t)b << 16) + row0);
        #pragma unroll
        for (int p = 0; p < 4; ++p) {
            const int fi = (p << 8) + t;      // 0..1023
            const int d  = fi >> 4;
            const int r4 = fi & 15;
            *(float4*)&xs[(d << 6) + (r4 << 2)] = xb4[(d << 8) + r4];
        }
    }
    // ---- stage ce2 from ws ----
    if (t < 128) ((float4*)ce2)[t] = ((const float4*)(wsc + WS_CE2))[t];

    // ---- prefetch chunk 0 of transposed codebook into registers ----
    float4 pv0, pv1, pv2, pv3, pv4, pv5, pv6, pv7;
    PREFETCH(0);

    __syncthreads();
    // ---- ||x_r||^2 fp32, sequential fmaf over d (bit-exact) ----
    if (t < 64) {
        float s = 0.f;
        for (int d = 0; d < 64; ++d) { const float v = xs[(d << 6) + t]; s = fmaf(v, v, s); }
        sxx[t] = s;
    }

    f16v acc0 = 0.f, acc1 = 0.f, acc2 = 0.f, acc3 = 0.f;
    f16v acc4 = 0.f, acc5 = 0.f, acc6 = 0.f, acc7 = 0.f;

    // ---- GEMM: 4 chunks of 128 codes (kc literal -> all acc indices literal) ----
    GEMM_CHUNK(0);
    GEMM_CHUNK(1);
    GEMM_CHUNK(2);
    GEMM_CHUNK(3);

    // ---- epilogue: ref-exact fp32 dist; per-row argmin + softmax(-dist) ----
    float* enc = out + OFF_ENC;
    float invz0, invz1, invz2, invz3, invz4, invz5, invz6, invz7;
    ROW_EPI(0, acc0, invz0);
    ROW_EPI(1, acc1, invz1);
    ROW_EPI(2, acc2, invz2);
    ROW_EPI(3, acc3, invz3);
    ROW_EPI(4, acc4, invz4);
    ROW_EPI(5, acc5, invz5);
    ROW_EPI(6, acc6, invz6);
    ROW_EPI(7, acc7, invz7);

    __syncthreads();   // all csT reads done; sidx visible

    // ---- softmax histogram: block-reduce in LDS (alias csT), partial to ws ----
    float* shist = csT;
    shist[t] = 0.f; shist[t + 256] = 0.f;
    __syncthreads();
    HIST_C(0)  HIST_C(1)  HIST_C(2)  HIST_C(3)
    HIST_C(4)  HIST_C(5)  HIST_C(6)  HIST_C(7)
    HIST_C(8)  HIST_C(9)  HIST_C(10) HIST_C(11)
    HIST_C(12) HIST_C(13) HIST_C(14) HIST_C(15)
    __syncthreads();
    {
        float* wsh = wso + WS_SHP + ((size_t)blk << 9);
        wsh[t]       = shist[t];
        wsh[t + 256] = shist[t + 256];
    }

    // ---- quantized output + loss partial (from sidx), vectorized ----
    const int r4 = (t & 15) << 2;          // row quad 0..60
    const int dq = t >> 4;                 // 0..15
    const int c0 = sidx[r4], c1 = sidx[r4 + 1], c2 = sidx[r4 + 2], c3 = sidx[r4 + 3];
    float lsum = 0.f;
    #pragma unroll
    for (int p = 0; p < 4; ++p) {
        const int d = (p << 4) + dq;
        float4 q;
        q.x = cb[(c0 << 6) + d];
        q.y = cb[(c1 << 6) + d];
        q.z = cb[(c2 << 6) + d];
        q.w = cb[(c3 << 6) + d];
        const float4 xv = *(const float4*)&xs[(d << 6) + r4];
        const float d0 = q.x - xv.x, d1 = q.y - xv.y, d2 = q.z - xv.z, d3 = q.w - xv.w;
        lsum = fmaf(d0, d0, lsum); lsum = fmaf(d1, d1, lsum);
        lsum = fmaf(d2, d2, lsum); lsum = fmaf(d3, d3, lsum);
        *(float4*)&out[(((size_t)(b << 6) + d) << 10) + row0 + r4] = q;
    }
    #pragma unroll
    for (int off = 1; off < 64; off <<= 1) lsum += __shfl_xor(lsum, off, 64);
    if ((t & 63) == 0) wso[WS_LOSS + (blk << 2) + (t >> 6)] = lsum;
}

// per-batch: sum 16 sh partials; rebuild ip histogram from enc indices
__global__ __launch_bounds__(512) void vq_reduce(const float* __restrict__ ws,
                                                 float* __restrict__ out)
{
    __shared__ int hist[512];
    const int b = blockIdx.x, t = threadIdx.x;
    const float* p = ws + WS_SHP + ((size_t)b << 13) + t;   // b*16*512
    float s = 0.f;
    #pragma unroll
    for (int j = 0; j < 16; ++j) s += p[j << 9];
    out[OFF_SH + (b << 9) + t] = s;
    hist[t] = 0;
    __syncthreads();
    const float* enc = out + OFF_ENC + ((size_t)b << 10);
    const int ca = (int)enc[t];
    const int cbn = (int)enc[t + 512];
    atomicAdd(&hist[ca], 1);
    atomicAdd(&hist[cbn], 1);
    __syncthreads();
    out[OFF_IP + (b << 9) + t] = (float)hist[t];
}

// loss sum + perplexity from per-batch code counts (512 threads, one k each)
__global__ __launch_bounds__(512) void vq_final(const float* __restrict__ ws,
                                                float* __restrict__ out)
{
    __shared__ float red[8], red2[8];
    const int t = threadIdx.x;
    const float* ip = out + OFF_IP;
    float c0 = 0.f, c1 = 0.f, c2 = 0.f, c3 = 0.f;
    #pragma unroll
    for (int bb = 0; bb < 64; bb += 4) {
        c0 += ip[((bb + 0) << 9) + t];
        c1 += ip[((bb + 1) << 9) + t];
        c2 += ip[((bb + 2) << 9) + t];
        c3 += ip[((bb + 3) << 9) + t];
    }
    const float c = (c0 + c1) + (c2 + c3);
    const float pav = c * (1.0f / 65536.f);
    float h = pav * logf(pav + 1e-10f);
    // loss partials: 4096 floats
    const float* wl = ws + WS_LOSS;
    float ls = 0.f;
    #pragma unroll
    for (int j = 0; j < 8; ++j) ls += wl[(j << 9) + t];
    #pragma unroll
    for (int off = 1; off < 64; off <<= 1) {
        h  += __shfl_xor(h, off, 64);
        ls += __shfl_xor(ls, off, 64);
    }
    if ((t & 63) == 0) { red[t >> 6] = h; red2[t >> 6] = ls; }
    __syncthreads();
    if (t == 0) {
        float H = 0.f, L = 0.f;
        #pragma unroll
        for (int w = 0; w < 8; ++w) { H += red[w]; L += red2[w]; }
        out[OFF_PERP] = expf(-H);
        out[OFF_LOSS] = L * (1.25f / 4194304.f);
    }
}

extern "C" void kernel_launch(void* const* d_in, const int* in_sizes, int n_in,
                              void* d_out, int out_size, void* d_ws, size_t ws_size,
                              hipStream_t stream)
{
    const float* x  = (const float*)d_in[0];
    const float* cb = (const float*)d_in[1];
    float* out = (float*)d_out;
    float* ws  = (float*)d_ws;
    (void)ws_size;   // requires >= 2.25 MB (561664 floats)

    vq_prep  <<<32,   256, 0, stream>>>(cb, ws);
    vq_main  <<<1024, 256, 0, stream>>>(x, cb, ws, ws, out);
    vq_reduce<<<64,   512, 0, stream>>>(ws, out);
    vq_final <<<1,    512, 0, stream>>>(ws, out);
}

// Round 7
// 172.895 us; speedup vs baseline: 1.1885x; 1.1885x over previous
//
#include <hip/hip_runtime.h>

// Problem constants (fixed by setup_inputs):
//   x: [B=64, D=64, H=32, W=32] fp32   -> N = B*H*W = 65536 rows of D=64
//   codebook: [K=512, D=64] fp32
// Output layout (all fp32, concatenated flat in return order):
//   [0 .. 4194304)        quant_out [B,D,H,W]
//   [4194304]             loss
//   [4194305]             perplexity
//   [4194306 .. +65536)   encoding_indice [B, H*W] (as float)
//   [4259842 .. +32768)   index_program [B,K]
//   [4292610 .. +32768)   softmax_histogram [B,K]

#define OFF_LOSS 4194304
#define OFF_PERP 4194305
#define OFF_ENC  4194306
#define OFF_IP   4259842
#define OFF_SH   4292610

// Workspace layout (floats). Requires ws_size >= 561664*4 B = 2.25 MB.
#define WS_CBT   0
#define WS_CE2   32768
#define WS_SHP   33280
#define WS_LOSS  557568

// R14 change (transport only; math bit-identical to R13):
//  - R13 post-mortem: 8x16 tile cut LDS work as designed, but total register
//    footprint (128 acc in the unified VGPR/AGPR file + 132 arch VGPR) =
//    ~260/wave -> 1 wave/SIMD (Occupancy 11%) -> latency-bound, 144 us.
//  - Fix: delete the 32 pv staging registers. csT chunks and the xs tile are
//    staged with __builtin_amdgcn_global_load_lds width=16 (both layouts are
//    lane-linear: lds = base + lane*16 for each staging wave, so the
//    wave-uniform-base+lane*size HW rule is satisfied). Single csT buffer:
//    issue 8 loads, barrier (compiler drains vmcnt), compute. ~400 L2-hot
//    cycles exposed per chunk << 16K compute cycles, hidden by co-resident
//    blocks. Total regs ~150-170 -> 2-3 waves/SIMD, LDS 50.5 KB -> up to 3
//    blocks/CU.

typedef float f16v __attribute__((ext_vector_type(16)));

typedef __attribute__((address_space(1))) const void g_void;
typedef __attribute__((address_space(3))) void lds_void;
#define GLOAD_LDS(G, S) \
    __builtin_amdgcn_global_load_lds((g_void*)(G), (lds_void*)(S), 16, 0, 0)

__global__ __launch_bounds__(256) void vq_prep(const float* __restrict__ cb,
                                               float* __restrict__ ws)
{
    const int t  = blockIdx.x * 256 + threadIdx.x;   // 0..8191
    const int kg = t >> 4;                           // code 0..511
    const int j  = t & 15;                           // float4 index along D
    const float4 v = ((const float4*)cb)[(kg << 4) + j];
    float pr = v.x * v.x + v.y * v.y + v.z * v.z + v.w * v.w;
    #pragma unroll
    for (int off = 1; off < 16; off <<= 1) pr += __shfl_xor(pr, off, 16);
    if (j == 0) ws[WS_CE2 + kg] = pr;
    // transposed, chunk-major: ws[WS_CBT + kc*8192 + d*128 + kl]
    const int kc = kg >> 7, kl = kg & 127;
    float* base = ws + WS_CBT + (kc << 13) + (j << 9) + kl;   // d = 4*j
    base[0]   = v.x;
    base[128] = v.y;
    base[256] = v.z;
    base[384] = v.w;
}

// ---- macro kit: all acc element indices are integer literals ----
#define FMA4(ACC, AV, K4) \
    ACC[(K4) + 0] = fmaf((AV), bq.x, ACC[(K4) + 0]); \
    ACC[(K4) + 1] = fmaf((AV), bq.y, ACC[(K4) + 1]); \
    ACC[(K4) + 2] = fmaf((AV), bq.z, ACC[(K4) + 2]); \
    ACC[(K4) + 3] = fmaf((AV), bq.w, ACC[(K4) + 3]);

// stage one 128-code chunk of cbT into csT via direct global->LDS DMA
#define STAGE_CST(KC) do { \
    GLOAD_LDS(&cbT4[((KC) << 11) + t],        &csT4[t]); \
    GLOAD_LDS(&cbT4[((KC) << 11) + 256 + t],  &csT4[256 + t]); \
    GLOAD_LDS(&cbT4[((KC) << 11) + 512 + t],  &csT4[512 + t]); \
    GLOAD_LDS(&cbT4[((KC) << 11) + 768 + t],  &csT4[768 + t]); \
    GLOAD_LDS(&cbT4[((KC) << 11) + 1024 + t], &csT4[1024 + t]); \
    GLOAD_LDS(&cbT4[((KC) << 11) + 1280 + t], &csT4[1280 + t]); \
    GLOAD_LDS(&cbT4[((KC) << 11) + 1536 + t], &csT4[1536 + t]); \
    GLOAD_LDS(&cbT4[((KC) << 11) + 1792 + t], &csT4[1792 + t]); \
} while (0)

// 64-d FMA sweep over the staged chunk. Per (row,k): d ascending within
// chunk, chunks ascending -- same fmaf chain as R12/R13.
#define GEMM_COMPUTE(KC) do { \
    _Pragma("unroll 2") \
    for (int db = 0; db < 16; ++db) { \
        const float* cbase = &csT[(db << 9) + (tc << 2)]; \
        _Pragma("unroll") \
        for (int j = 0; j < 4; ++j) { \
            const int d = (db << 2) + j; \
            const float4 a0 = *(const float4*)&xs[(d << 6) + (tr << 3)]; \
            const float4 a1 = *(const float4*)&xs[(d << 6) + (tr << 3) + 4]; \
            const float4 bq = *(const float4*)&cbase[j << 7]; \
            FMA4(acc0, a0.x, (KC) << 2) \
            FMA4(acc1, a0.y, (KC) << 2) \
            FMA4(acc2, a0.z, (KC) << 2) \
            FMA4(acc3, a0.w, (KC) << 2) \
            FMA4(acc4, a1.x, (KC) << 2) \
            FMA4(acc5, a1.y, (KC) << 2) \
            FMA4(acc6, a1.z, (KC) << 2) \
            FMA4(acc7, a1.w, (KC) << 2) \
        } \
    } \
} while (0)

#define EPI_C(C, ACC) { \
    const int k = (((C) >> 2) << 7) + (tc << 2) + ((C) & 3); \
    const float t1 = xxr + ce2[k]; \
    const float dist = t1 - 2.f * ACC[C]; \
    ACC[C] = dist; \
    if (dist < m) { m = dist; bk = k; } }

#define EXP_C(C, ACC) { \
    const float e = __expf(m - ACC[C]); \
    ACC[C] = e; z += e; }

#define ROW_EPI(I, ACC, INVZ) do { \
    const int row = (tr << 3) + (I); \
    const float xxr = sxx[row]; \
    float m = 1e30f; int bk = 0; \
    EPI_C(0, ACC)  EPI_C(1, ACC)  EPI_C(2, ACC)  EPI_C(3, ACC) \
    EPI_C(4, ACC)  EPI_C(5, ACC)  EPI_C(6, ACC)  EPI_C(7, ACC) \
    EPI_C(8, ACC)  EPI_C(9, ACC)  EPI_C(10, ACC) EPI_C(11, ACC) \
    EPI_C(12, ACC) EPI_C(13, ACC) EPI_C(14, ACC) EPI_C(15, ACC) \
    _Pragma("unroll") \
    for (int off = 1; off < 32; off <<= 1) { \
        const float mo = __shfl_xor(m, off, 32); \
        const int   ko = __shfl_xor(bk, off, 32); \
        if (mo < m || (mo == m && ko < bk)) { m = mo; bk = ko; } \
    } \
    float z = 0.f; \
    EXP_C(0, ACC)  EXP_C(1, ACC)  EXP_C(2, ACC)  EXP_C(3, ACC) \
    EXP_C(4, ACC)  EXP_C(5, ACC)  EXP_C(6, ACC)  EXP_C(7, ACC) \
    EXP_C(8, ACC)  EXP_C(9, ACC)  EXP_C(10, ACC) EXP_C(11, ACC) \
    EXP_C(12, ACC) EXP_C(13, ACC) EXP_C(14, ACC) EXP_C(15, ACC) \
    _Pragma("unroll") \
    for (int off = 1; off < 32; off <<= 1) z += __shfl_xor(z, off, 32); \
    INVZ = 1.f / z; \
    if (tc == 0) { \
        sidx[row] = bk; \
        enc[((size_t)b << 10) + row0 + row] = (float)bk; \
    } \
} while (0)

#define HIST_C(C) { \
    const int k = (((C) >> 2) << 7) + (tc << 2) + ((C) & 3); \
    float cs = 0.f; \
    cs += acc0[C] * invz0; cs += acc1[C] * invz1; \
    cs += acc2[C] * invz2; cs += acc3[C] * invz3; \
    cs += acc4[C] * invz4; cs += acc5[C] * invz5; \
    cs += acc6[C] * invz6; cs += acc7[C] * invz7; \
    atomicAdd(&shist[k], cs); }

__global__ __launch_bounds__(256, 1) void vq_main(
    const float* __restrict__ x, const float* __restrict__ cb,
    const float* __restrict__ wsc,   // cbT + ce2 (read-only region)
    float* __restrict__ wso,         // sh + loss partials (write-only region)
    float* __restrict__ out)
{
    __shared__ float  xs[64 * 64];     // xs[d*64 + r], transposed x tile (64 rows)
    __shared__ float  csT[64 * 128];   // [d][k] for current 128-code chunk
    __shared__ float  ce2[512];        // ||e_k||^2 (fp32)
    __shared__ float  sxx[64];         // ||x_r||^2 (fp32) per row
    __shared__ int    sidx[64];        // argmin code per row

    const int t    = threadIdx.x;
    const int blk  = blockIdx.x;        // 0..1023
    const int b    = blk >> 4;          // batch index
    const int row0 = (blk & 15) << 6;   // row offset within batch (H*W space)
    const int tr   = t >> 5;            // 0..7  (row group: rows tr*8..tr*8+7)
    const int tc   = t & 31;            // 0..31 (col group)

    const float4* cbT4 = (const float4*)(wsc + WS_CBT);
    float4* csT4 = (float4*)csT;

    // ---- stage x tile via global->LDS DMA (lane-linear: lds = base+lane*16) ----
    {
        const float4* xb4 = (const float4*)(x + ((size_t)b << 16) + row0);
        #pragma unroll
        for (int p = 0; p < 4; ++p) {
            const int fi = (p << 8) + t;      // 0..1023
            const int d  = fi >> 4;
            const int r4 = fi & 15;
            GLOAD_LDS(&xb4[(d << 8) + r4], &xs[(d << 6) + (r4 << 2)]);
        }
    }
    // ---- stage chunk 0 of codebook ----
    STAGE_CST(0);
    // ---- stage ce2 from ws (plain load/store, drained by the barrier) ----
    if (t < 128) ((float4*)ce2)[t] = ((const float4*)(wsc + WS_CE2))[t];

    __syncthreads();   // drains vmcnt(0): xs + csT chunk 0 + ce2 ready

    // ---- ||x_r||^2 fp32, sequential fmaf over d (bit-exact) ----
    if (t < 64) {
        float s = 0.f;
        for (int d = 0; d < 64; ++d) { const float v = xs[(d << 6) + t]; s = fmaf(v, v, s); }
        sxx[t] = s;
    }

    f16v acc0 = 0.f, acc1 = 0.f, acc2 = 0.f, acc3 = 0.f;
    f16v acc4 = 0.f, acc5 = 0.f, acc6 = 0.f, acc7 = 0.f;

    // ---- GEMM: 4 chunks of 128 codes (kc literal -> all acc indices literal) ----
    GEMM_COMPUTE(0);
    __syncthreads();   // all waves done reading csT chunk 0
    STAGE_CST(1);
    __syncthreads();   // vmcnt drained: chunk 1 ready (sxx also visible)
    GEMM_COMPUTE(1);
    __syncthreads();
    STAGE_CST(2);
    __syncthreads();
    GEMM_COMPUTE(2);
    __syncthreads();
    STAGE_CST(3);
    __syncthreads();
    GEMM_COMPUTE(3);

    // ---- epilogue: ref-exact fp32 dist; per-row argmin + softmax(-dist) ----
    float* enc = out + OFF_ENC;
    float invz0, invz1, invz2, invz3, invz4, invz5, invz6, invz7;
    ROW_EPI(0, acc0, invz0);
    ROW_EPI(1, acc1, invz1);
    ROW_EPI(2, acc2, invz2);
    ROW_EPI(3, acc3, invz3);
    ROW_EPI(4, acc4, invz4);
    ROW_EPI(5, acc5, invz5);
    ROW_EPI(6, acc6, invz6);
    ROW_EPI(7, acc7, invz7);

    __syncthreads();   // all csT reads done; sidx visible

    // ---- softmax histogram: block-reduce in LDS (alias csT), partial to ws ----
    float* shist = csT;
    shist[t] = 0.f; shist[t + 256] = 0.f;
    __syncthreads();
    HIST_C(0)  HIST_C(1)  HIST_C(2)  HIST_C(3)
    HIST_C(4)  HIST_C(5)  HIST_C(6)  HIST_C(7)
    HIST_C(8)  HIST_C(9)  HIST_C(10) HIST_C(11)
    HIST_C(12) HIST_C(13) HIST_C(14) HIST_C(15)
    __syncthreads();
    {
        float* wsh = wso + WS_SHP + ((size_t)blk << 9);
        wsh[t]       = shist[t];
        wsh[t + 256] = shist[t + 256];
    }

    // ---- quantized output + loss partial (from sidx), vectorized ----
    const int r4 = (t & 15) << 2;          // row quad 0..60
    const int dq = t >> 4;                 // 0..15
    const int c0 = sidx[r4], c1 = sidx[r4 + 1], c2 = sidx[r4 + 2], c3 = sidx[r4 + 3];
    float lsum = 0.f;
    #pragma unroll
    for (int p = 0; p < 4; ++p) {
        const int d = (p << 4) + dq;
        float4 q;
        q.x = cb[(c0 << 6) + d];
        q.y = cb[(c1 << 6) + d];
        q.z = cb[(c2 << 6) + d];
        q.w = cb[(c3 << 6) + d];
        const float4 xv = *(const float4*)&xs[(d << 6) + r4];
        const float d0 = q.x - xv.x, d1 = q.y - xv.y, d2 = q.z - xv.z, d3 = q.w - xv.w;
        lsum = fmaf(d0, d0, lsum); lsum = fmaf(d1, d1, lsum);
        lsum = fmaf(d2, d2, lsum); lsum = fmaf(d3, d3, lsum);
        *(float4*)&out[(((size_t)(b << 6) + d) << 10) + row0 + r4] = q;
    }
    #pragma unroll
    for (int off = 1; off < 64; off <<= 1) lsum += __shfl_xor(lsum, off, 64);
    if ((t & 63) == 0) wso[WS_LOSS + (blk << 2) + (t >> 6)] = lsum;
}

// per-batch: sum 16 sh partials; rebuild ip histogram from enc indices
__global__ __launch_bounds__(512) void vq_reduce(const float* __restrict__ ws,
                                                 float* __restrict__ out)
{
    __shared__ int hist[512];
    const int b = blockIdx.x, t = threadIdx.x;
    const float* p = ws + WS_SHP + ((size_t)b << 13) + t;   // b*16*512
    float s = 0.f;
    #pragma unroll
    for (int j = 0; j < 16; ++j) s += p[j << 9];
    out[OFF_SH + (b << 9) + t] = s;
    hist[t] = 0;
    __syncthreads();
    const float* enc = out + OFF_ENC + ((size_t)b << 10);
    const int ca = (int)enc[t];
    const int cbn = (int)enc[t + 512];
    atomicAdd(&hist[ca], 1);
    atomicAdd(&hist[cbn], 1);
    __syncthreads();
    out[OFF_IP + (b << 9) + t] = (float)hist[t];
}

// loss sum + perplexity from per-batch code counts (512 threads, one k each)
__global__ __launch_bounds__(512) void vq_final(const float* __restrict__ ws,
                                                float* __restrict__ out)
{
    __shared__ float red[8], red2[8];
    const int t = threadIdx.x;
    const float* ip = out + OFF_IP;
    float c0 = 0.f, c1 = 0.f, c2 = 0.f, c3 = 0.f;
    #pragma unroll
    for (int bb = 0; bb < 64; bb += 4) {
        c0 += ip[((bb + 0) << 9) + t];
        c1 += ip[((bb + 1) << 9) + t];
        c2 += ip[((bb + 2) << 9) + t];
        c3 += ip[((bb + 3) << 9) + t];
    }
    const float c = (c0 + c1) + (c2 + c3);
    const float pav = c * (1.0f / 65536.f);
    float h = pav * logf(pav + 1e-10f);
    // loss partials: 4096 floats
    const float* wl = ws + WS_LOSS;
    float ls = 0.f;
    #pragma unroll
    for (int j = 0; j < 8; ++j) ls += wl[(j << 9) + t];
    #pragma unroll
    for (int off = 1; off < 64; off <<= 1) {
        h  += __shfl_xor(h, off, 64);
        ls += __shfl_xor(ls, off, 64);
    }
    if ((t & 63) == 0) { red[t >> 6] = h; red2[t >> 6] = ls; }
    __syncthreads();
    if (t == 0) {
        float H = 0.f, L = 0.f;
        #pragma unroll
        for (int w = 0; w < 8; ++w) { H += red[w]; L += red2[w]; }
        out[OFF_PERP] = expf(-H);
        out[OFF_LOSS] = L * (1.25f / 4194304.f);
    }
}

extern "C" void kernel_launch(void* const* d_in, const int* in_sizes, int n_in,
                              void* d_out, int out_size, void* d_ws, size_t ws_size,
                              hipStream_t stream)
{
    const float* x  = (const float*)d_in[0];
    const float* cb = (const float*)d_in[1];
    float* out = (float*)d_out;
    float* ws  = (float*)d_ws;
    (void)ws_size;   // requires >= 2.25 MB (561664 floats)

    vq_prep  <<<32,   256, 0, stream>>>(cb, ws);
    vq_main  <<<1024, 256, 0, stream>>>(x, cb, ws, ws, out);
    vq_reduce<<<64,   512, 0, stream>>>(ws, out);
    vq_final <<<1,    512, 0, stream>>>(ws, out);
}